// Round 1
// baseline (3175.325 us; speedup 1.0000x reference)
//
#include <hip/hip_runtime.h>

#define B_    64
#define T_    512
#define D_    512
#define KF    1024      // fused K = [h(512) ; x(512)]
#define NGRP  4         // batch groups
#define NSLC  16        // WG slices per group
#define GB    16        // batches per group

using short8 = __attribute__((ext_vector_type(8))) short;
using f32x4  = __attribute__((ext_vector_type(4))) float;

__device__ __forceinline__ unsigned short f2bf(float f) {
    unsigned int u = __float_as_uint(f);
    u = (u + 0x7fffu + ((u >> 16) & 1u)) >> 16;
    return (unsigned short)u;
}
__device__ __forceinline__ unsigned int pack_bf2(unsigned long long fl2) {
    float lo = __uint_as_float((unsigned int)fl2);
    float hi = __uint_as_float((unsigned int)(fl2 >> 32));
    return (unsigned int)f2bf(lo) | ((unsigned int)f2bf(hi) << 16);
}
__device__ __forceinline__ float sigmf(float x)  { return 1.0f / (1.0f + __expf(-x)); }
__device__ __forceinline__ float tanh_f(float x) { return 1.0f - 2.0f / (1.0f + __expf(2.0f * x)); }

// ---- prep: X fp32 -> bf16 ----
__global__ void prep_x(const float* __restrict__ X, unsigned short* __restrict__ Xb, int n4) {
    int stride = gridDim.x * blockDim.x;
    for (int i = blockIdx.x * blockDim.x + threadIdx.x; i < n4; i += stride) {
        float4 v = ((const float4*)X)[i];
        ushort4 o;
        o.x = f2bf(v.x); o.y = f2bf(v.y); o.z = f2bf(v.z); o.w = f2bf(v.w);
        ((ushort4*)Xb)[i] = o;
    }
}

// ---- prep: fused weight Wcat[r = o*4+g][k] bf16; k<512 -> U_g[o][k], k>=512 -> W'_g[o][k-512]
// gate g: 0=i (Ui,Wi), 1=f (Uf,Wi  <- source quirk), 2=c (Uc,Wc), 3=o (Uo,Wo)
__global__ void prep_w(const float* __restrict__ Wi, const float* __restrict__ Wc,
                       const float* __restrict__ Wo,
                       const float* __restrict__ Ui, const float* __restrict__ Uf,
                       const float* __restrict__ Uc, const float* __restrict__ Uo,
                       unsigned short* __restrict__ Wcat) {
    int idx = blockIdx.x * blockDim.x + threadIdx.x;
    if (idx >= 2048 * 1024) return;
    int r = idx >> 10, k = idx & 1023;
    int o = r >> 2, g = r & 3;
    const float* U = (g == 0) ? Ui : (g == 1) ? Uf : (g == 2) ? Uc : Uo;
    const float* W = (g < 2) ? Wi : (g == 2) ? Wc : Wo;
    float v = (k < 512) ? U[o * 512 + k] : W[o * 512 + (k - 512)];
    Wcat[idx] = f2bf(v);
}

// ---- persistent recurrence kernel ----
// grid = 64 WGs: group g = bid>>4 (16 batches), slice s = bid&15 (32 output cols, 4 gates = 128 rows)
__launch_bounds__(512, 2)
__global__ void lstm_rec(const unsigned short* __restrict__ Xb,
                         const unsigned short* __restrict__ Wcat,
                         float* __restrict__ hbuf,         // [2][64][512] fp32 (agent-scope)
                         unsigned int* __restrict__ cnt,   // [NGRP][T_]
                         float* __restrict__ out,          // H then C
                         const float* __restrict__ bi, const float* __restrict__ bc,
                         const float* __restrict__ bo, const float* __restrict__ bUf,
                         const float* __restrict__ bUc, const float* __restrict__ bUo) {
    __shared__ unsigned char Albs[16 * 2048];   // A tile [16 rows][1024 k] bf16, XOR-swizzled
    __shared__ float S[2][128][20];             // [k-half][row][batch(padded)]

    const int tid  = threadIdx.x;
    const int bid  = blockIdx.x;
    const int g    = bid >> 4;
    const int s    = bid & 15;
    const int wave = tid >> 6;
    const int lane = tid & 63;
    const int np   = wave >> 1;   // 0..3 : rows [np*32, np*32+32)
    const int kh   = wave & 1;    // k-half

    unsigned int* mycnt = cnt + g * T_;

    // ---- one-time: load B fragments (16 rows x 512 k per acc) into VGPRs ----
    short8 Bf0[16], Bf1[16];
    {
        const int r0 = s * 128 + np * 32;
        const int ln = lane & 15, kq = lane >> 4;
        #pragma unroll
        for (int kt = 0; kt < 16; ++kt) {
            int k = kh * 512 + kt * 32 + kq * 8;
            Bf0[kt] = *(const short8*)(Wcat + (size_t)(r0 + ln) * KF + k);
            Bf1[kt] = *(const short8*)(Wcat + (size_t)(r0 + 16 + ln) * KF + k);
        }
    }

    // ---- elementwise identity: one thread per (batch, output col) ----
    const int oo = tid & 31, bb = tid >> 5;           // bb 0..15
    const int og = s * 32 + oo;
    const int Bg_ew = g * GB + bb;
    const float bias_i = bi[og];
    const float bias_f = bi[og] + bUf[og];            // f-gate uses xi's bias + bUf
    const float bias_c = bc[og] + bUc[og];
    const float bias_o = bo[og] + bUo[og];
    float c_state = 0.0f;

    // ---- staging identity ----
    const int srow = tid >> 5;    // batch row 0..15
    const int sseg = tid & 31;    // 16 elems each
    const int Bg_st = g * GB + srow;
    const int sxor = (srow & 7) << 4;

    float* Hout = out;
    float* Cout = out + (size_t)B_ * T_ * D_;

    // MFMA read constants
    const int arow  = lane & 15;
    const int abase = arow * 2048;
    const int axor  = (arow & 7) << 4;
    const int kq16  = (lane >> 4) * 16;

    for (int t = 0; t < T_; ++t) {
        // ---- stage A = [h_{t-1} ; X_t] into LDS (bf16, swizzled) ----
        {
            const float* hsrc = hbuf + ((size_t)((t + 1) & 1) * B_ + Bg_st) * D_ + sseg * 16;
            unsigned int u0 = pack_bf2(__hip_atomic_load((const unsigned long long*)hsrc + 0, __ATOMIC_RELAXED, __HIP_MEMORY_SCOPE_AGENT));
            unsigned int u1 = pack_bf2(__hip_atomic_load((const unsigned long long*)hsrc + 1, __ATOMIC_RELAXED, __HIP_MEMORY_SCOPE_AGENT));
            unsigned int u2 = pack_bf2(__hip_atomic_load((const unsigned long long*)hsrc + 2, __ATOMIC_RELAXED, __HIP_MEMORY_SCOPE_AGENT));
            unsigned int u3 = pack_bf2(__hip_atomic_load((const unsigned long long*)hsrc + 3, __ATOMIC_RELAXED, __HIP_MEMORY_SCOPE_AGENT));
            unsigned int u4 = pack_bf2(__hip_atomic_load((const unsigned long long*)hsrc + 4, __ATOMIC_RELAXED, __HIP_MEMORY_SCOPE_AGENT));
            unsigned int u5 = pack_bf2(__hip_atomic_load((const unsigned long long*)hsrc + 5, __ATOMIC_RELAXED, __HIP_MEMORY_SCOPE_AGENT));
            unsigned int u6 = pack_bf2(__hip_atomic_load((const unsigned long long*)hsrc + 6, __ATOMIC_RELAXED, __HIP_MEMORY_SCOPE_AGENT));
            unsigned int u7 = pack_bf2(__hip_atomic_load((const unsigned long long*)hsrc + 7, __ATOMIC_RELAXED, __HIP_MEMORY_SCOPE_AGENT));
            uint4 hv0 = make_uint4(u0, u1, u2, u3);
            uint4 hv1 = make_uint4(u4, u5, u6, u7);
            int kb = sseg * 32;
            *(uint4*)(Albs + srow * 2048 + ((kb)      ^ sxor)) = hv0;
            *(uint4*)(Albs + srow * 2048 + ((kb + 16) ^ sxor)) = hv1;

            const unsigned short* xsrc = Xb + ((size_t)Bg_st * T_ + t) * D_ + sseg * 16;
            uint4 xv0 = ((const uint4*)xsrc)[0];
            uint4 xv1 = ((const uint4*)xsrc)[1];
            int kbx = 1024 + sseg * 32;
            *(uint4*)(Albs + srow * 2048 + ((kbx)      ^ sxor)) = xv0;
            *(uint4*)(Albs + srow * 2048 + ((kbx + 16) ^ sxor)) = xv1;
        }
        __syncthreads();

        // ---- MFMA: acc over this wave's k-half for 2 n-tiles ----
        {
            f32x4 acc0 = {0.f, 0.f, 0.f, 0.f};
            f32x4 acc1 = {0.f, 0.f, 0.f, 0.f};
            #pragma unroll
            for (int kt = 0; kt < 16; ++kt) {
                int kbyte = kh * 1024 + kt * 64 + kq16;
                short8 a = *(const short8*)(Albs + abase + (kbyte ^ axor));
                acc0 = __builtin_amdgcn_mfma_f32_16x16x32_bf16(a, Bf0[kt], acc0, 0, 0, 0);
                acc1 = __builtin_amdgcn_mfma_f32_16x16x32_bf16(a, Bf1[kt], acc1, 0, 0, 0);
            }
            // D layout: m = (lane>>4)*4 + reg (batch), n = lane&15 (row)
            const int n0 = np * 32 + (lane & 15);
            const int mb = (lane >> 4) * 4;
            *(f32x4*)&S[kh][n0][mb]      = acc0;
            *(f32x4*)&S[kh][n0 + 16][mb] = acc1;
        }
        __syncthreads();

        // ---- elementwise gates + state update + stores ----
        {
            int r = oo * 4;
            float s0 = S[0][r + 0][bb] + S[1][r + 0][bb];
            float s1 = S[0][r + 1][bb] + S[1][r + 1][bb];
            float s2 = S[0][r + 2][bb] + S[1][r + 2][bb];
            float s3 = S[0][r + 3][bb] + S[1][r + 3][bb];
            float iv = sigmf(s0 + bias_i);
            float fv = sigmf(s1 + bias_f);
            float cc = tanh_f(s2 + bias_c);
            float ov = sigmf(s3 + bias_o);
            float cn = fv * c_state + iv * cc;
            float hv = ov * tanh_f(cn);
            c_state = cn;
            size_t oidx = ((size_t)Bg_ew * T_ + t) * D_ + og;
            Hout[oidx] = hv;
            Cout[oidx] = cn;
            __hip_atomic_store((unsigned int*)hbuf + ((size_t)(t & 1) * B_ + Bg_ew) * D_ + og,
                               __float_as_uint(hv), __ATOMIC_RELAXED, __HIP_MEMORY_SCOPE_AGENT);
        }
        __syncthreads();   // drains all waves' stores (vmcnt 0) before arrive

        if (tid == 0 && t < T_ - 1) {
            __hip_atomic_fetch_add(mycnt + t, 1u, __ATOMIC_RELEASE, __HIP_MEMORY_SCOPE_AGENT);
            while (__hip_atomic_load(mycnt + t, __ATOMIC_ACQUIRE, __HIP_MEMORY_SCOPE_AGENT) < NSLC) { }
        }
        __syncthreads();
    }
}

extern "C" void kernel_launch(void* const* d_in, const int* in_sizes, int n_in,
                              void* d_out, int out_size, void* d_ws, size_t ws_size,
                              hipStream_t stream) {
    const float* X   = (const float*)d_in[0];
    const float* Wi  = (const float*)d_in[1];
    const float* bi  = (const float*)d_in[2];
    // d_in[3] = Wf, d_in[4] = bf : unused by reference semantics
    const float* Wc  = (const float*)d_in[5];
    const float* bc  = (const float*)d_in[6];
    const float* Wo  = (const float*)d_in[7];
    const float* bo  = (const float*)d_in[8];
    const float* Ui  = (const float*)d_in[9];
    const float* Uf  = (const float*)d_in[10];
    const float* bUf = (const float*)d_in[11];
    const float* Uc  = (const float*)d_in[12];
    const float* bUc = (const float*)d_in[13];
    const float* Uo  = (const float*)d_in[14];
    const float* bUo = (const float*)d_in[15];

    char* ws = (char*)d_ws;
    const size_t XB_BYTES   = (size_t)B_ * T_ * D_ * 2;   // 33,554,432
    const size_t WCAT_BYTES = (size_t)2048 * 1024 * 2;    //  4,194,304
    const size_t HBUF_BYTES = (size_t)2 * B_ * D_ * 4;    //    262,144
    const size_t CNT_BYTES  = (size_t)NGRP * T_ * 4;      //      8,192

    unsigned short* Xb   = (unsigned short*)ws;
    unsigned short* Wcat = (unsigned short*)(ws + XB_BYTES);
    float*          hbuf = (float*)(ws + XB_BYTES + WCAT_BYTES);
    unsigned int*   cnt  = (unsigned int*)(ws + XB_BYTES + WCAT_BYTES + HBUF_BYTES);

    // zero h (t=0 reads hbuf[1]) and the barrier counters, every call
    hipMemsetAsync(hbuf, 0, HBUF_BYTES + CNT_BYTES, stream);

    prep_x<<<2048, 256, 0, stream>>>(X, Xb, B_ * T_ * D_ / 4);
    prep_w<<<8192, 256, 0, stream>>>(Wi, Wc, Wo, Ui, Uf, Uc, Uo, Wcat);
    lstm_rec<<<NGRP * NSLC, 512, 0, stream>>>(Xb, Wcat, hbuf, cnt, (float*)d_out,
                                              bi, bc, bo, bUf, bUc, bUo);
}

// Round 2
// 2032.531 us; speedup vs baseline: 1.5623x; 1.5623x over previous
//
#include <hip/hip_runtime.h>

#define B_    64
#define T_    512
#define D_    512
#define KF    1024      // fused K = [h(512) ; x(512)]
#define NGRP  4         // batch groups
#define NSLC  16        // WG slices per group
#define GB    16        // batches per group

using short8 = __attribute__((ext_vector_type(8))) short;
using f32x4  = __attribute__((ext_vector_type(4))) float;

__device__ __forceinline__ unsigned short f2bf(float f) {
    unsigned int u = __float_as_uint(f);
    u = (u + 0x7fffu + ((u >> 16) & 1u)) >> 16;
    return (unsigned short)u;
}
__device__ __forceinline__ float sigmf(float x)  { return 1.0f / (1.0f + __expf(-x)); }
__device__ __forceinline__ float tanh_f(float x) { return 1.0f - 2.0f / (1.0f + __expf(2.0f * x)); }

// ---- prep: X fp32 -> bf16 ----
__global__ void prep_x(const float* __restrict__ X, unsigned short* __restrict__ Xb, int n4) {
    int stride = gridDim.x * blockDim.x;
    for (int i = blockIdx.x * blockDim.x + threadIdx.x; i < n4; i += stride) {
        float4 v = ((const float4*)X)[i];
        ushort4 o;
        o.x = f2bf(v.x); o.y = f2bf(v.y); o.z = f2bf(v.z); o.w = f2bf(v.w);
        ((ushort4*)Xb)[i] = o;
    }
}

// ---- prep: fused weight Wcat[r = o*4+g][k]; gate g: 0=i(Ui,Wi) 1=f(Uf,Wi quirk) 2=c(Uc,Wc) 3=o(Uo,Wo)
__global__ void prep_w(const float* __restrict__ Wi, const float* __restrict__ Wc,
                       const float* __restrict__ Wo,
                       const float* __restrict__ Ui, const float* __restrict__ Uf,
                       const float* __restrict__ Uc, const float* __restrict__ Uo,
                       unsigned short* __restrict__ Wcat) {
    int idx = blockIdx.x * blockDim.x + threadIdx.x;
    if (idx >= 2048 * 1024) return;
    int r = idx >> 10, k = idx & 1023;
    int o = r >> 2, g = r & 3;
    const float* U = (g == 0) ? Ui : (g == 1) ? Uf : (g == 2) ? Uc : Uo;
    const float* W = (g < 2) ? Wi : (g == 2) ? Wc : Wo;
    float v = (k < 512) ? U[o * 512 + k] : W[o * 512 + (k - 512)];
    Wcat[idx] = f2bf(v);
}

// ---- persistent recurrence kernel ----
// 64 WGs: group g = bid>>4 (16 batches), slice s = bid&15 (128 gate-rows = 32 ocols)
// 8 waves = (mp 0..3) x (kh 0..1): wave owns 2 M-tiles (32 gate-rows), one K-half (512)
__launch_bounds__(512, 2)
__global__ void lstm_rec(const unsigned short* __restrict__ Xb,
                         const unsigned short* __restrict__ Wcat,
                         unsigned short* __restrict__ hbuf,   // [2][64][512] bf16
                         unsigned int* __restrict__ cnt,      // [NGRP][T_]
                         float* __restrict__ out,             // H then C (fp32)
                         const float* __restrict__ bi, const float* __restrict__ bc,
                         const float* __restrict__ bo, const float* __restrict__ bUf,
                         const float* __restrict__ bUc, const float* __restrict__ bUo) {
    __shared__ unsigned char Albs[16 * 2048];   // act tile [16 b][1024 k] bf16, XOR-swizzled
    __shared__ float Sp[8 * 16 * 20];           // kh=1 partials: [tile8][b] stride 5 quads
    __shared__ float Hx[16][34];                // h transpose buffer (pad 34: 2-way max)
    __shared__ unsigned int wcnt;
    __shared__ int go;

    const int tid  = threadIdx.x;
    const int bid  = blockIdx.x;
    const int g    = bid >> 4;
    const int s    = bid & 15;
    const int wave = tid >> 6;
    const int lane = tid & 63;
    const int mp   = wave >> 1;
    const int kh   = wave & 1;
    const int q    = lane >> 4;
    const int bl   = lane & 15;

    if (tid == 0) { wcnt = 0u; go = 0; }

    unsigned int* flag = cnt + (size_t)g * T_;

    // ---- one-time: weight A-fragments into VGPRs (2 tiles x 16 ksteps x 4 VGPR = 128) ----
    short8 Wf0[16], Wf1[16];
    {
        const int r0 = s * 128 + mp * 32;
        const int kb = kh * 512 + q * 8;
        #pragma unroll
        for (int kt = 0; kt < 16; ++kt) {
            Wf0[kt] = *(const short8*)(Wcat + (size_t)(r0 + bl) * KF + kb + kt * 32);
            Wf1[kt] = *(const short8*)(Wcat + (size_t)(r0 + 16 + bl) * KF + kb + kt * 32);
        }
    }

    // ---- per-lane gate identity (kh==0 waves do elementwise): batch bl, ocols og0, og0+4 ----
    const int og0 = s * 32 + mp * 8 + q;
    const float bi0 = bi[og0],       bf0v = bi[og0] + bUf[og0];
    const float bc0v = bc[og0] + bUc[og0], bo0v = bo[og0] + bUo[og0];
    const float bi1 = bi[og0 + 4],   bf1v = bi[og0 + 4] + bUf[og0 + 4];
    const float bc1v = bc[og0 + 4] + bUc[og0 + 4], bo1v = bo[og0 + 4] + bUo[og0 + 4];
    float c0s = 0.0f, c1s = 0.0f;

    // ---- staging identity ----
    const int sb  = tid >> 5;     // batch row 0..15
    const int seg = tid & 31;     // 16 bf16 (32 B) each
    const int sx  = (sb & 7) << 4;
    const size_t xrow = (size_t)(g * GB + sb) * T_ * D_;

    // MFMA B-frag read constants
    const int abase = bl * 2048;
    const int axor  = (bl & 7) << 4;
    const int kq16  = q * 16;

    float* Hout = out;
    float* Cout = out + (size_t)B_ * T_ * D_;
    const size_t orow = (size_t)(g * GB + bl) * T_ * D_ + s * 32 + mp * 8 + q;

    // prefetch X[0]
    uint4 xr0, xr1;
    {
        const uint4* xs = (const uint4*)(Xb + xrow + seg * 16);
        xr0 = xs[0]; xr1 = xs[1];
    }
    __syncthreads();

    for (int t = 0; t < T_; ++t) {
        // ---- wait for h_{t-1} globally visible ----
        if (t > 0) {
            if (tid == 0) {
                while (__hip_atomic_load(flag + (t - 1), __ATOMIC_RELAXED, __HIP_MEMORY_SCOPE_AGENT) < NSLC) { }
                __hip_atomic_store(&go, t, __ATOMIC_RELAXED, __HIP_MEMORY_SCOPE_WORKGROUP);
            } else if (lane == 0) {
                while (__hip_atomic_load(&go, __ATOMIC_RELAXED, __HIP_MEMORY_SCOPE_WORKGROUP) < t) { }
            }
        }

        // ---- stage A = [h_{t-1} ; X_t] into LDS ----
        {
            const unsigned short* hsrc = hbuf + ((size_t)((t + 1) & 1) * B_ + g * GB + sb) * D_ + seg * 16;
            unsigned long long h0 = __hip_atomic_load((const unsigned long long*)hsrc + 0, __ATOMIC_RELAXED, __HIP_MEMORY_SCOPE_AGENT);
            unsigned long long h1 = __hip_atomic_load((const unsigned long long*)hsrc + 1, __ATOMIC_RELAXED, __HIP_MEMORY_SCOPE_AGENT);
            unsigned long long h2 = __hip_atomic_load((const unsigned long long*)hsrc + 2, __ATOMIC_RELAXED, __HIP_MEMORY_SCOPE_AGENT);
            unsigned long long h3 = __hip_atomic_load((const unsigned long long*)hsrc + 3, __ATOMIC_RELAXED, __HIP_MEMORY_SCOPE_AGENT);
            *(uint4*)(Albs + sb * 2048 + ((seg * 32)      ^ sx)) =
                make_uint4((unsigned)h0, (unsigned)(h0 >> 32), (unsigned)h1, (unsigned)(h1 >> 32));
            *(uint4*)(Albs + sb * 2048 + ((seg * 32 + 16) ^ sx)) =
                make_uint4((unsigned)h2, (unsigned)(h2 >> 32), (unsigned)h3, (unsigned)(h3 >> 32));
            *(uint4*)(Albs + sb * 2048 + ((1024 + seg * 32)      ^ sx)) = xr0;
            *(uint4*)(Albs + sb * 2048 + ((1024 + seg * 32 + 16) ^ sx)) = xr1;
        }
        // prefetch X[t+1] (hides under MFMA)
        {
            int tn = (t + 1 < T_) ? (t + 1) : t;
            const uint4* xs = (const uint4*)(Xb + xrow + (size_t)tn * D_ + seg * 16);
            xr0 = xs[0]; xr1 = xs[1];
        }
        __syncthreads();

        // ---- MFMA: 2 tiles x 16 ksteps (this wave's K-half) ----
        f32x4 acc0 = {0.f, 0.f, 0.f, 0.f};
        f32x4 acc1 = {0.f, 0.f, 0.f, 0.f};
        #pragma unroll
        for (int kt = 0; kt < 16; ++kt) {
            int kbyte = (kh * 16 + kt) * 64 + kq16;
            short8 a = *(const short8*)(Albs + abase + (kbyte ^ axor));
            acc0 = __builtin_amdgcn_mfma_f32_16x16x32_bf16(Wf0[kt], a, acc0, 0, 0, 0);
            acc1 = __builtin_amdgcn_mfma_f32_16x16x32_bf16(Wf1[kt], a, acc1, 0, 0, 0);
        }
        if (kh == 1) {
            *(f32x4*)&Sp[((mp * 2 + 0) * 16 + bl) * 20 + q * 4] = acc0;
            *(f32x4*)&Sp[((mp * 2 + 1) * 16 + bl) * 20 + q * 4] = acc1;
        }
        __syncthreads();

        float hv0, hv1, cn0, cn1;
        if (kh == 0) {
            acc0 += *(const f32x4*)&Sp[((mp * 2 + 0) * 16 + bl) * 20 + q * 4];
            acc1 += *(const f32x4*)&Sp[((mp * 2 + 1) * 16 + bl) * 20 + q * 4];
            float iv = sigmf(acc0[0] + bi0);
            float fv = sigmf(acc0[1] + bf0v);
            float cc = tanh_f(acc0[2] + bc0v);
            float ov = sigmf(acc0[3] + bo0v);
            cn0 = fv * c0s + iv * cc;
            hv0 = ov * tanh_f(cn0);
            c0s = cn0;
            iv = sigmf(acc1[0] + bi1);
            fv = sigmf(acc1[1] + bf1v);
            cc = tanh_f(acc1[2] + bc1v);
            ov = sigmf(acc1[3] + bo1v);
            cn1 = fv * c1s + iv * cc;
            hv1 = ov * tanh_f(cn1);
            c1s = cn1;
            Hx[bl][mp * 8 + q]     = hv0;
            Hx[bl][mp * 8 + 4 + q] = hv1;
        }
        __syncthreads();

        // ---- pack h -> bf16 hbuf (coalesced), signal ----
        if (tid < 256) {
            int b = tid >> 4, cp = tid & 15;
            unsigned int u = (unsigned int)f2bf(Hx[b][2 * cp]) |
                             ((unsigned int)f2bf(Hx[b][2 * cp + 1]) << 16);
            unsigned int* dst = (unsigned int*)(hbuf + ((size_t)(t & 1) * B_ + g * GB + b) * D_ + s * 32 + cp * 2);
            __hip_atomic_store(dst, u, __ATOMIC_RELAXED, __HIP_MEMORY_SCOPE_AGENT);
            asm volatile("s_waitcnt vmcnt(0)" ::: "memory");
            if (lane == 0) {
                if (atomicAdd(&wcnt, 1u) == 3u) {       // last of 4 pack waves
                    __hip_atomic_store(&wcnt, 0u, __ATOMIC_RELAXED, __HIP_MEMORY_SCOPE_WORKGROUP);
                    __hip_atomic_fetch_add(flag + t, 1u, __ATOMIC_RELAXED, __HIP_MEMORY_SCOPE_AGENT);
                }
            }
        }

        // ---- streaming H/C outputs (off the flag-critical path) ----
        if (kh == 0) {
            size_t o0 = orow + (size_t)t * D_;
            Hout[o0]     = hv0;
            Hout[o0 + 4] = hv1;
            Cout[o0]     = cn0;
            Cout[o0 + 4] = cn1;
        }
    }
}

extern "C" void kernel_launch(void* const* d_in, const int* in_sizes, int n_in,
                              void* d_out, int out_size, void* d_ws, size_t ws_size,
                              hipStream_t stream) {
    const float* X   = (const float*)d_in[0];
    const float* Wi  = (const float*)d_in[1];
    const float* bi  = (const float*)d_in[2];
    // d_in[3] = Wf, d_in[4] = bf : unused by reference semantics
    const float* Wc  = (const float*)d_in[5];
    const float* bc  = (const float*)d_in[6];
    const float* Wo  = (const float*)d_in[7];
    const float* bo  = (const float*)d_in[8];
    const float* Ui  = (const float*)d_in[9];
    const float* Uf  = (const float*)d_in[10];
    const float* bUf = (const float*)d_in[11];
    const float* Uc  = (const float*)d_in[12];
    const float* bUc = (const float*)d_in[13];
    const float* Uo  = (const float*)d_in[14];
    const float* bUo = (const float*)d_in[15];

    char* ws = (char*)d_ws;
    const size_t XB_BYTES   = (size_t)B_ * T_ * D_ * 2;   // 33,554,432
    const size_t WCAT_BYTES = (size_t)2048 * 1024 * 2;    //  4,194,304
    const size_t HBUF_BYTES = (size_t)2 * B_ * D_ * 2;    //    131,072 (bf16)
    const size_t CNT_BYTES  = (size_t)NGRP * T_ * 4;      //      8,192

    unsigned short* Xb   = (unsigned short*)ws;
    unsigned short* Wcat = (unsigned short*)(ws + XB_BYTES);
    unsigned short* hbuf = (unsigned short*)(ws + XB_BYTES + WCAT_BYTES);
    unsigned int*   cnt  = (unsigned int*)(ws + XB_BYTES + WCAT_BYTES + HBUF_BYTES);

    // zero h (t=0 reads buffer 1) and the per-step flags, every call
    hipMemsetAsync(hbuf, 0, HBUF_BYTES + CNT_BYTES, stream);

    prep_x<<<2048, 256, 0, stream>>>(X, Xb, B_ * T_ * D_ / 4);
    prep_w<<<8192, 256, 0, stream>>>(Wi, Wc, Wo, Ui, Uf, Uc, Uo, Wcat);
    lstm_rec<<<NGRP * NSLC, 512, 0, stream>>>(Xb, Wcat, hbuf, cnt, (float*)d_out,
                                              bi, bc, bo, bUf, bUc, bUo);
}